// Round 3
// baseline (430.970 us; speedup 1.0000x reference)
//
#include <hip/hip_runtime.h>
#include <hip/hip_bf16.h>

typedef __bf16 bf16;
typedef __bf16 bf16x2 __attribute__((ext_vector_type(2)));
typedef __bf16 bf16x4 __attribute__((ext_vector_type(4)));
typedef __bf16 bf16x8 __attribute__((ext_vector_type(8)));
typedef float f32x4 __attribute__((ext_vector_type(4)));

#define NF 40
#define HW 256
#define KPAD 384         // 9 taps * 40 ci padded to 12*32
#define MPAD 48          // 40 co padded to 3*16

// ws layout: W3A[48*384] | W4A[48*384] | W2A[48*64] | pad | gated bf16 NHWC
#define GATED_ELEM_OFF 40960
#define WS_NEEDED (GATED_ELEM_OFF * 2 + (size_t)16 * HW * HW * NF * 2)

// ---------------- weight prep ----------------
__global__ void prep_weights(const float* __restrict__ w2,
                             const float* __restrict__ w3,
                             const float* __restrict__ w4,
                             bf16* __restrict__ ws) {
  int i = blockIdx.x * 256 + threadIdx.x;
  const int T = MPAD * KPAD;               // 18432
  if (i < T) {
    int co = i / KPAD, k = i % KPAD;
    float v3 = 0.f, v4 = 0.f;
    if (co < NF && k < 360) {
      int tap = k / NF, ci = k - tap * NF;
      int ky = tap / 3, kx = tap - ky * 3;
      int idx = ((co * NF + ci) * 3 + ky) * 3 + kx;
      v3 = w3[idx];
      v4 = w4[idx];
    }
    ws[i] = (bf16)v3;
    ws[T + i] = (bf16)v4;
  }
  if (i < MPAD * 64) {
    int co = i / 64, ci = i - co * 64;
    float v = 0.f;
    if (co < NF && ci < NF) v = w2[co * NF + ci];
    ws[2 * T + i] = (bf16)v;
  }
}

// ---------------- K1: gated = conv3x3(x,w3) * sigmoid(conv1x1(x,w2)+b2) ----------------
// tile 16x16, region 18x18, writes bf16 NHWC
#define K1_RW 18
__global__ __launch_bounds__(512, 6)
void k1_gate(const float* __restrict__ x, const float* __restrict__ b2,
             const bf16* __restrict__ ws, bf16* __restrict__ gated) {
  __shared__ bf16 xs[K1_RW * K1_RW * NF];  // 25920 B, [y][x][ci]

  const int tid  = threadIdx.x;
  const int lane = tid & 63;
  const int wid  = tid >> 6;
  const int l15  = lane & 15;
  const int lk   = lane >> 4;
  const int n    = blockIdx.z;
  const int X0   = blockIdx.x * 16;
  const int Y0   = blockIdx.y * 16;

  const bf16* W3A = ws;
  const bf16* W2A = ws + 2 * MPAD * KPAD;

  // stage x region [Y0-1, Y0+17) x [X0-1, X0+17), ci-innermost, ci pairs
  const float* xn = x + (size_t)n * NF * HW * HW;
  for (int i = tid; i < K1_RW * K1_RW * NF / 2; i += 512) {
    int cih = i / (K1_RW * K1_RW);
    int rem = i - cih * (K1_RW * K1_RW);
    int ci  = cih * 2;
    int yy  = rem / K1_RW, xx = rem - yy * K1_RW;
    int gy  = Y0 - 1 + yy, gx = X0 - 1 + xx;
    float v0 = 0.f, v1 = 0.f;
    if ((unsigned)gy < HW && (unsigned)gx < HW) {
      const float* p = xn + (size_t)ci * HW * HW + gy * HW + gx;
      v0 = p[0];
      v1 = p[HW * HW];
    }
    bf16x2 pr; pr[0] = (bf16)v0; pr[1] = (bf16)v1;
    *(bf16x2*)&xs[rem * NF + ci] = pr;
  }

  // per-lane precompute
  int off3[12];
#pragma unroll
  for (int kk = 0; kk < 12; ++kk) {
    int k0 = kk * 32 + lk * 8;
    int kc = (k0 < 360) ? k0 : 0;
    int tap = kc / NF, ci0 = kc - tap * NF;
    int ky = tap / 3, kx = tap - ky * 3;
    off3[kk] = (ky * K1_RW + kx) * NF + ci0;
  }
  int pb[2];
#pragma unroll
  for (int t2 = 0; t2 < 2; ++t2) {
    int pix = (wid * 2 + t2) * 16 + l15;   // 0..255
    int py = pix >> 4, px = pix & 15;
    pb[t2] = (py * K1_RW + px) * NF;
  }
  float b2v[3][4];
#pragma unroll
  for (int mt = 0; mt < 3; ++mt)
#pragma unroll
    for (int r = 0; r < 4; ++r) {
      int co = mt * 16 + lk * 4 + r;
      b2v[mt][r] = (co < NF) ? b2[co] : 0.f;
    }

  __syncthreads();

  // gate GEMM (K=64)
  bf16x4 gv[2][3];
  {
    f32x4 g[2][3];
#pragma unroll
    for (int t2 = 0; t2 < 2; ++t2)
#pragma unroll
      for (int mt = 0; mt < 3; ++mt) g[t2][mt] = f32x4{0, 0, 0, 0};
#pragma unroll
    for (int kk = 0; kk < 2; ++kk) {
      int k0 = kk * 32 + lk * 8;
      int goff = (K1_RW + 1) * NF + ((k0 < NF) ? k0 : 0);
      bf16x8 a[3];
#pragma unroll
      for (int mt = 0; mt < 3; ++mt)
        a[mt] = *(const bf16x8*)&W2A[(mt * 16 + l15) * 64 + k0];
#pragma unroll
      for (int t2 = 0; t2 < 2; ++t2) {
        bf16x8 b = *(const bf16x8*)&xs[pb[t2] + goff];
#pragma unroll
        for (int mt = 0; mt < 3; ++mt)
          g[t2][mt] = __builtin_amdgcn_mfma_f32_16x16x32_bf16(a[mt], b, g[t2][mt], 0, 0, 0);
      }
    }
#pragma unroll
    for (int t2 = 0; t2 < 2; ++t2)
#pragma unroll
      for (int mt = 0; mt < 3; ++mt)
#pragma unroll
        for (int r = 0; r < 4; ++r)
          gv[t2][mt][r] = (bf16)(1.f / (1.f + __expf(-(g[t2][mt][r] + b2v[mt][r]))));
  }

  // main W3 GEMM (K=384), A streamed per kk
  f32x4 facc[2][3];
#pragma unroll
  for (int t2 = 0; t2 < 2; ++t2)
#pragma unroll
    for (int mt = 0; mt < 3; ++mt) facc[t2][mt] = f32x4{0, 0, 0, 0};

#pragma unroll
  for (int kk = 0; kk < 12; ++kk) {
    bf16x8 a[3];
#pragma unroll
    for (int mt = 0; mt < 3; ++mt)
      a[mt] = *(const bf16x8*)&W3A[(mt * 16 + l15) * KPAD + kk * 32 + lk * 8];
#pragma unroll
    for (int t2 = 0; t2 < 2; ++t2) {
      bf16x8 b = *(const bf16x8*)&xs[pb[t2] + off3[kk]];
#pragma unroll
      for (int mt = 0; mt < 3; ++mt)
        facc[t2][mt] = __builtin_amdgcn_mfma_f32_16x16x32_bf16(a[mt], b, facc[t2][mt], 0, 0, 0);
    }
  }

  // epilogue: gated NHWC bf16
#pragma unroll
  for (int t2 = 0; t2 < 2; ++t2) {
    int pix = (wid * 2 + t2) * 16 + l15;
    int py = pix >> 4, px = pix & 15;
    size_t base = ((size_t)n * HW * HW + (size_t)(Y0 + py) * HW + (X0 + px)) * NF;
#pragma unroll
    for (int mt = 0; mt < 3; ++mt) {
      int co0 = mt * 16 + lk * 4;
      if (co0 < NF) {
        bf16x4 ov;
#pragma unroll
        for (int r = 0; r < 4; ++r)
          ov[r] = (bf16)(facc[t2][mt][r] * (float)gv[t2][mt][r]);
        *(bf16x4*)&gated[base + co0] = ov;
      }
    }
  }
}

// ---------------- K2: out = conv3x3(gated, w4), f32 NCHW ----------------
// tile 32 wide x 8 tall, region 34x10
#define K2_RW 34
#define K2_RH 10
__global__ __launch_bounds__(512, 6)
void k2_conv(const bf16* __restrict__ gated, const bf16* __restrict__ ws,
             float* __restrict__ out) {
  __shared__ bf16 os[K2_RH * K2_RW * NF];  // 27200 B

  const int tid  = threadIdx.x;
  const int lane = tid & 63;
  const int wid  = tid >> 6;
  const int l15  = lane & 15;
  const int lk   = lane >> 4;
  const int n    = blockIdx.z;
  const int X0   = blockIdx.x * 32;
  const int Y0   = blockIdx.y * 8;

  const bf16* W4A = ws + MPAD * KPAD;

  // stage gated region [Y0-1,Y0+9) x [X0-1,X0+33), 16B units
  for (int i = tid; i < K2_RH * K2_RW * 5; i += 512) {   // 1700 units
    int r   = i / (K2_RW * 5);
    int rem = i - r * (K2_RW * 5);
    int p   = rem / 5, c = rem - p * 5;
    int gy  = Y0 - 1 + r, gx = X0 - 1 + p;
    bf16x8 v = {};
    if ((unsigned)gy < HW && (unsigned)gx < HW)
      v = *(const bf16x8*)&gated[((size_t)n * HW * HW + (size_t)gy * HW + gx) * NF + c * 8];
    *(bf16x8*)&os[(r * K2_RW + p) * NF + c * 8] = v;
  }

  int off4[12];
#pragma unroll
  for (int kk = 0; kk < 12; ++kk) {
    int k0 = kk * 32 + lk * 8;
    int kc = (k0 < 360) ? k0 : 0;
    int tap = kc / NF, ci0 = kc - tap * NF;
    int ky = tap / 3, kx = tap - ky * 3;
    off4[kk] = (ky * K2_RW + kx) * NF + ci0;
  }
  int pb2[2];
#pragma unroll
  for (int t2 = 0; t2 < 2; ++t2) {
    int pix = (wid * 2 + t2) * 16 + l15;   // 0..255
    int py = pix >> 5, px = pix & 31;
    pb2[t2] = (py * K2_RW + px) * NF;
  }

  __syncthreads();

  f32x4 acc[2][3];
#pragma unroll
  for (int t2 = 0; t2 < 2; ++t2)
#pragma unroll
    for (int mt = 0; mt < 3; ++mt) acc[t2][mt] = f32x4{0, 0, 0, 0};

#pragma unroll
  for (int kk = 0; kk < 12; ++kk) {
    bf16x8 a[3];
#pragma unroll
    for (int mt = 0; mt < 3; ++mt)
      a[mt] = *(const bf16x8*)&W4A[(mt * 16 + l15) * KPAD + kk * 32 + lk * 8];
#pragma unroll
    for (int t2 = 0; t2 < 2; ++t2) {
      bf16x8 b = *(const bf16x8*)&os[pb2[t2] + off4[kk]];
#pragma unroll
      for (int mt = 0; mt < 3; ++mt)
        acc[t2][mt] = __builtin_amdgcn_mfma_f32_16x16x32_bf16(a[mt], b, acc[t2][mt], 0, 0, 0);
    }
  }

  float* on = out + (size_t)n * NF * HW * HW;
#pragma unroll
  for (int t2 = 0; t2 < 2; ++t2) {
    int pix = (wid * 2 + t2) * 16 + l15;
    int py = pix >> 5, px = pix & 31;
#pragma unroll
    for (int mt = 0; mt < 3; ++mt)
#pragma unroll
      for (int r = 0; r < 4; ++r) {
        int co = mt * 16 + lk * 4 + r;
        if (co < NF)
          on[(size_t)co * HW * HW + (Y0 + py) * HW + (X0 + px)] = acc[t2][mt][r];
      }
  }
}

// ---------------- fallback: fused single-kernel (R2 version) ----------------
#define TS 16
#define XR 20
#define OR 18
__global__ __launch_bounds__(512, 4)
void paconv_fused(const float* __restrict__ x,
                  const float* __restrict__ b2,
                  const bf16* __restrict__ ws,
                  float* __restrict__ out) {
  __shared__ bf16 xs[XR * XR * NF];
  __shared__ bf16 o1[OR * OR * NF];

  const int tid  = threadIdx.x;
  const int lane = tid & 63;
  const int wid  = tid >> 6;
  const int l15  = lane & 15;
  const int lk   = lane >> 4;
  const int n    = blockIdx.z;
  const int X0   = blockIdx.x * TS;
  const int Y0   = blockIdx.y * TS;

  const bf16* W3A = ws;
  const bf16* W4A = ws + MPAD * KPAD;
  const bf16* W2A = ws + 2 * MPAD * KPAD;

  const float* xn = x + (size_t)n * NF * HW * HW;
  for (int i = tid; i < XR * XR * NF / 2; i += 512) {
    int cih = i / (XR * XR);
    int rem = i - cih * (XR * XR);
    int ci  = cih * 2;
    int yy  = rem / XR, xx = rem - yy * XR;
    int gy  = Y0 - 2 + yy, gx = X0 - 2 + xx;
    float v0 = 0.f, v1 = 0.f;
    if ((unsigned)gy < HW && (unsigned)gx < HW) {
      const float* p = xn + (size_t)ci * HW * HW + gy * HW + gx;
      v0 = p[0];
      v1 = p[HW * HW];
    }
    bf16x2 pr; pr[0] = (bf16)v0; pr[1] = (bf16)v1;
    *(bf16x2*)&xs[rem * NF + ci] = pr;
  }

  int off3[12];
#pragma unroll
  for (int kk = 0; kk < 12; ++kk) {
    int k0 = kk * 32 + lk * 8;
    int kc = (k0 < 360) ? k0 : 0;
    int tap = kc / NF, ci0 = kc - tap * NF;
    int ky = tap / 3, kx = tap - ky * 3;
    off3[kk] = (ky * XR + kx) * NF + ci0;
  }

  int pb[3], pixv[3];
  float keepv[3];
  bool realv[3];
#pragma unroll
  for (int ni = 0; ni < 3; ++ni) {
    int nt   = wid + ni * 8;
    int pixr = nt * 16 + l15;
    bool real = pixr < 324;
    int pix  = real ? pixr : 323;
    int py = pix / OR, px = pix - py * OR;
    pb[ni]   = (py * XR + px) * NF;
    pixv[ni] = pix;
    realv[ni] = real;
    int gy1 = Y0 - 1 + py, gx1 = X0 - 1 + px;
    keepv[ni] = (((unsigned)gy1 < HW) && ((unsigned)gx1 < HW)) ? 1.f : 0.f;
  }

  __syncthreads();

  {
    float b2v[3][4];
#pragma unroll
    for (int mt = 0; mt < 3; ++mt)
#pragma unroll
      for (int r = 0; r < 4; ++r) {
        int co = mt * 16 + lk * 4 + r;
        b2v[mt][r] = (co < NF) ? b2[co] : 0.f;
      }
    int goff[2];
#pragma unroll
    for (int kk = 0; kk < 2; ++kk) {
      int k0 = kk * 32 + lk * 8;
      goff[kk] = (XR + 1) * NF + ((k0 < NF) ? k0 : 0);
    }
    bf16x8 a2[2][3];
#pragma unroll
    for (int kk = 0; kk < 2; ++kk)
#pragma unroll
      for (int mt = 0; mt < 3; ++mt)
        a2[kk][mt] = *(const bf16x8*)&W2A[(mt * 16 + l15) * 64 + kk * 32 + lk * 8];

#pragma unroll
    for (int ni = 0; ni < 3; ++ni) {
      f32x4 g[3] = {f32x4{0,0,0,0}, f32x4{0,0,0,0}, f32x4{0,0,0,0}};
#pragma unroll
      for (int kk = 0; kk < 2; ++kk) {
        bf16x8 b = *(const bf16x8*)&xs[pb[ni] + goff[kk]];
#pragma unroll
        for (int mt = 0; mt < 3; ++mt)
          g[mt] = __builtin_amdgcn_mfma_f32_16x16x32_bf16(a2[kk][mt], b, g[mt], 0, 0, 0);
      }
      if (realv[ni]) {
#pragma unroll
        for (int mt = 0; mt < 3; ++mt) {
          int co0 = mt * 16 + lk * 4;
          if (co0 < NF) {
            bf16x4 gvv;
#pragma unroll
            for (int r = 0; r < 4; ++r)
              gvv[r] = (bf16)(1.f / (1.f + __expf(-(g[mt][r] + b2v[mt][r]))));
            *(bf16x4*)&o1[pixv[ni] * NF + co0] = gvv;
          }
        }
      }
    }
  }

  {
    f32x4 facc[3][3];
#pragma unroll
    for (int ni = 0; ni < 3; ++ni)
#pragma unroll
      for (int mt = 0; mt < 3; ++mt)
        facc[ni][mt] = f32x4{0, 0, 0, 0};

#pragma unroll
    for (int q = 0; q < 4; ++q) {
      bf16x8 a3[3][3];
#pragma unroll
      for (int kk = 0; kk < 3; ++kk)
#pragma unroll
        for (int mt = 0; mt < 3; ++mt)
          a3[kk][mt] = *(const bf16x8*)
              &W3A[(mt * 16 + l15) * KPAD + (q * 3 + kk) * 32 + lk * 8];
#pragma unroll
      for (int ni = 0; ni < 3; ++ni)
#pragma unroll
        for (int kk = 0; kk < 3; ++kk) {
          bf16x8 b = *(const bf16x8*)&xs[pb[ni] + off3[q * 3 + kk]];
#pragma unroll
          for (int mt = 0; mt < 3; ++mt)
            facc[ni][mt] = __builtin_amdgcn_mfma_f32_16x16x32_bf16(
                a3[kk][mt], b, facc[ni][mt], 0, 0, 0);
        }
    }

#pragma unroll
    for (int ni = 0; ni < 3; ++ni) {
      if (realv[ni]) {
#pragma unroll
        for (int mt = 0; mt < 3; ++mt) {
          int co0 = mt * 16 + lk * 4;
          if (co0 < NF) {
            bf16x4 gvv = *(const bf16x4*)&o1[pixv[ni] * NF + co0];
            bf16x4 ov;
#pragma unroll
            for (int r = 0; r < 4; ++r)
              ov[r] = (bf16)(facc[ni][mt][r] * (float)gvv[r] * keepv[ni]);
            *(bf16x4*)&o1[pixv[ni] * NF + co0] = ov;
          }
        }
      }
    }
  }

  __syncthreads();

  {
    int off4[12];
#pragma unroll
    for (int kk = 0; kk < 12; ++kk) {
      int k0 = kk * 32 + lk * 8;
      int kc = (k0 < 360) ? k0 : 0;
      int tap = kc / NF, ci0 = kc - tap * NF;
      int ky = tap / 3, kx = tap - ky * 3;
      off4[kk] = (ky * OR + kx) * NF + ci0;
    }
    int pb2[2];
#pragma unroll
    for (int t2 = 0; t2 < 2; ++t2)
      pb2[t2] = ((wid * 2 + t2) * OR + l15) * NF;

    f32x4 acc2[2][3];
#pragma unroll
    for (int t2 = 0; t2 < 2; ++t2)
#pragma unroll
      for (int mt = 0; mt < 3; ++mt)
        acc2[t2][mt] = f32x4{0, 0, 0, 0};

#pragma unroll
    for (int q = 0; q < 4; ++q) {
      bf16x8 a4[3][3];
#pragma unroll
      for (int kk = 0; kk < 3; ++kk)
#pragma unroll
        for (int mt = 0; mt < 3; ++mt)
          a4[kk][mt] = *(const bf16x8*)
              &W4A[(mt * 16 + l15) * KPAD + (q * 3 + kk) * 32 + lk * 8];
#pragma unroll
      for (int t2 = 0; t2 < 2; ++t2)
#pragma unroll
        for (int kk = 0; kk < 3; ++kk) {
          bf16x8 b = *(const bf16x8*)&o1[pb2[t2] + off4[q * 3 + kk]];
#pragma unroll
          for (int mt = 0; mt < 3; ++mt)
            acc2[t2][mt] = __builtin_amdgcn_mfma_f32_16x16x32_bf16(
                a4[kk][mt], b, acc2[t2][mt], 0, 0, 0);
        }
    }

    float* on = out + (size_t)n * NF * HW * HW;
#pragma unroll
    for (int t2 = 0; t2 < 2; ++t2) {
      int oy = wid * 2 + t2;
#pragma unroll
      for (int mt = 0; mt < 3; ++mt)
#pragma unroll
        for (int r = 0; r < 4; ++r) {
          int co = mt * 16 + lk * 4 + r;
          if (co < NF)
            on[(size_t)co * HW * HW + (Y0 + oy) * HW + (X0 + l15)] = acc2[t2][mt][r];
        }
    }
  }
}

extern "C" void kernel_launch(void* const* d_in, const int* in_sizes, int n_in,
                              void* d_out, int out_size, void* d_ws, size_t ws_size,
                              hipStream_t stream) {
  const float* x  = (const float*)d_in[0];
  const float* w2 = (const float*)d_in[1];
  const float* b2 = (const float*)d_in[2];
  const float* w3 = (const float*)d_in[3];
  const float* w4 = (const float*)d_in[4];
  float* out = (float*)d_out;
  bf16* ws   = (bf16*)d_ws;

  hipLaunchKernelGGL(prep_weights, dim3(72), dim3(256), 0, stream, w2, w3, w4, ws);

  if (ws_size >= WS_NEEDED) {
    bf16* gated = ws + GATED_ELEM_OFF;
    hipLaunchKernelGGL(k1_gate, dim3(16, 16, 16), dim3(512), 0, stream,
                       x, b2, ws, gated);
    hipLaunchKernelGGL(k2_conv, dim3(8, 32, 16), dim3(512), 0, stream,
                       gated, ws, out);
  } else {
    hipLaunchKernelGGL(paconv_fused, dim3(16, 16, 16), dim3(512), 0, stream,
                       x, b2, ws, out);
  }
}

// Round 5
// 426.284 us; speedup vs baseline: 1.0110x; 1.0110x over previous
//
#include <hip/hip_runtime.h>
#include <hip/hip_bf16.h>

typedef __bf16 bf16;
typedef __bf16 bf16x2 __attribute__((ext_vector_type(2)));
typedef __bf16 bf16x4 __attribute__((ext_vector_type(4)));
typedef __bf16 bf16x8 __attribute__((ext_vector_type(8)));
typedef float f32x4 __attribute__((ext_vector_type(4)));

#define NF 40
#define HW 256
#define KPAD 384
#define MPAD 48

// ws elem layout (bf16): weights[40960] | gated[16*256*256*40] | xT[16*256*256*40]
#define GATED_ELEM_OFF 40960
#define IMG_ELEMS ((size_t)16 * HW * HW * NF)
#define XT_ELEM_OFF (GATED_ELEM_OFF + IMG_ELEMS)
#define WS_SPLIT ((GATED_ELEM_OFF + IMG_ELEMS) * 2)          // 84.0 MB
#define WS_FULL  ((GATED_ELEM_OFF + 2 * IMG_ELEMS) * 2)      // 167.9 MB

// ---------------- weight prep ----------------
__global__ void prep_weights(const float* __restrict__ w2,
                             const float* __restrict__ w3,
                             const float* __restrict__ w4,
                             bf16* __restrict__ ws) {
  int i = blockIdx.x * 256 + threadIdx.x;
  const int T = MPAD * KPAD;
  if (i < T) {
    int co = i / KPAD, k = i % KPAD;
    float v3 = 0.f, v4 = 0.f;
    if (co < NF && k < 360) {
      int tap = k / NF, ci = k - tap * NF;
      int ky = tap / 3, kx = tap - ky * 3;
      int idx = ((co * NF + ci) * 3 + ky) * 3 + kx;
      v3 = w3[idx];
      v4 = w4[idx];
    }
    ws[i] = (bf16)v3;
    ws[T + i] = (bf16)v4;
  }
  if (i < MPAD * 64) {
    int co = i / 64, ci = i - co * 64;
    float v = 0.f;
    if (co < NF && ci < NF) v = w2[co * NF + ci];
    ws[2 * T + i] = (bf16)v;
  }
}

// ---------------- T: x NCHW f32 -> xT NHWC bf16 ----------------
// one block = one image row (256 px * 40 ch). 256 threads.
// LDS grouped: 5 groups of 8ci, group stride 2056 elems (4112 B; pads banks)
__global__ __launch_bounds__(256, 8)
void transpose_nhwc(const float* __restrict__ x, bf16* __restrict__ xT) {
  __shared__ bf16 xs[5 * 2056];
  const int tid = threadIdx.x;
  const int row = blockIdx.x;
  const int n   = blockIdx.y;
  const size_t nb = (size_t)n * NF * HW * HW + (size_t)row * HW;

  // read: thread=pixel, 4 planes per iter (coalesced 256B per wave per plane)
#pragma unroll
  for (int cc = 0; cc < 10; ++cc) {
    bf16x4 v;
#pragma unroll
    for (int j = 0; j < 4; ++j)
      v[j] = (bf16)x[nb + (size_t)(cc * 4 + j) * HW * HW + tid];
    *(bf16x4*)&xs[(cc >> 1) * 2056 + tid * 8 + (cc & 1) * 4] = v;
  }
  __syncthreads();

  // write: 2560 units of 8B, contiguous 20KB
  const size_t ob = ((size_t)n * HW * HW + (size_t)row * HW) * NF;
#pragma unroll
  for (int k = 0; k < 10; ++k) {
    int u = tid + k * 256;
    int px = u / 10, c4 = u - px * 10;
    bf16x4 v = *(const bf16x4*)&xs[(c4 >> 1) * 2056 + px * 8 + (c4 & 1) * 4];
    *(bf16x4*)&xT[ob + (size_t)u * 4] = v;
  }
}

// ---------------- K1 (xT path): gated = conv3x3(x,w3)*sigmoid(conv1x1+b) ----
// tile 16x16, region 18x18. LDS grouped: stride 2600 elems (5200 B).
__global__ __launch_bounds__(512, 8)
void k1_gate_xt(const bf16* __restrict__ xT, const float* __restrict__ b2,
                const bf16* __restrict__ ws, bf16* __restrict__ gated) {
  __shared__ bf16 xs[5 * 2600];            // 26000 B

  const int tid  = threadIdx.x;
  const int lane = tid & 63;
  const int wid  = tid >> 6;
  const int l15  = lane & 15;
  const int lk   = lane >> 4;
  const int n    = blockIdx.z;
  const int X0   = blockIdx.x * 16;
  const int Y0   = blockIdx.y * 16;

  const bf16* W3A = ws;
  const bf16* W2A = ws + 2 * MPAD * KPAD;

  // stage 18x18 region from xT (rows of 1440B contiguous)
  for (int i = tid; i < 1620; i += 512) {
    int r   = i / 90;
    int rem = i - r * 90;
    int p   = rem / 5, c = rem - p * 5;
    int gy  = Y0 - 1 + r, gx = X0 - 1 + p;
    bf16x8 v = {};
    if ((unsigned)gy < HW && (unsigned)gx < HW)
      v = *(const bf16x8*)&xT[((size_t)n * HW * HW + (size_t)gy * HW + gx) * NF + c * 8];
    *(bf16x8*)&xs[c * 2600 + (r * 18 + p) * 8] = v;
  }

  // per-lane precompute
  int gp3[12];
#pragma unroll
  for (int kk = 0; kk < 12; ++kk) {
    int k0 = kk * 32 + lk * 8;
    int kc = (k0 < 360) ? k0 : 0;
    int tap = kc / NF, ci0 = kc - tap * NF;
    int ky = tap / 3, kx = tap - ky * 3;
    gp3[kk] = (ci0 >> 3) * 2600 + (ky * 18 + kx) * 8;
  }
  int pbp[2], pixv[2];
#pragma unroll
  for (int t2 = 0; t2 < 2; ++t2) {
    int pix = (wid * 2 + t2) * 16 + l15;
    int py = pix >> 4, px = pix & 15;
    pbp[t2]  = py * 18 + px;
    pixv[t2] = pix;
  }
  float b2v[3][4];
#pragma unroll
  for (int mt = 0; mt < 3; ++mt)
#pragma unroll
    for (int r = 0; r < 4; ++r) {
      int co = mt * 16 + lk * 4 + r;
      b2v[mt][r] = (co < NF) ? b2[co] : 0.f;
    }

  __syncthreads();

  // gate GEMM (K=64): center tap
  bf16x4 gv[2][3];
  {
    f32x4 g[2][3];
#pragma unroll
    for (int t2 = 0; t2 < 2; ++t2)
#pragma unroll
      for (int mt = 0; mt < 3; ++mt) g[t2][mt] = f32x4{0, 0, 0, 0};
#pragma unroll
    for (int kk = 0; kk < 2; ++kk) {
      int k0 = kk * 32 + lk * 8;
      int ci0 = (k0 < NF) ? k0 : 0;
      int goff = (ci0 >> 3) * 2600 + 19 * 8;   // tap (1,1)
      bf16x8 a[3];
#pragma unroll
      for (int mt = 0; mt < 3; ++mt)
        a[mt] = *(const bf16x8*)&W2A[(mt * 16 + l15) * 64 + k0];
#pragma unroll
      for (int t2 = 0; t2 < 2; ++t2) {
        bf16x8 b = *(const bf16x8*)&xs[goff + pbp[t2] * 8];
#pragma unroll
        for (int mt = 0; mt < 3; ++mt)
          g[t2][mt] = __builtin_amdgcn_mfma_f32_16x16x32_bf16(a[mt], b, g[t2][mt], 0, 0, 0);
      }
    }
#pragma unroll
    for (int t2 = 0; t2 < 2; ++t2)
#pragma unroll
      for (int mt = 0; mt < 3; ++mt)
#pragma unroll
        for (int r = 0; r < 4; ++r)
          gv[t2][mt][r] = (bf16)(1.f / (1.f + __expf(-(g[t2][mt][r] + b2v[mt][r]))));
  }

  // main W3 GEMM (K=384)
  f32x4 facc[2][3];
#pragma unroll
  for (int t2 = 0; t2 < 2; ++t2)
#pragma unroll
    for (int mt = 0; mt < 3; ++mt) facc[t2][mt] = f32x4{0, 0, 0, 0};

#pragma unroll
  for (int kk = 0; kk < 12; ++kk) {
    bf16x8 a[3];
#pragma unroll
    for (int mt = 0; mt < 3; ++mt)
      a[mt] = *(const bf16x8*)&W3A[(mt * 16 + l15) * KPAD + kk * 32 + lk * 8];
#pragma unroll
    for (int t2 = 0; t2 < 2; ++t2) {
      bf16x8 b = *(const bf16x8*)&xs[gp3[kk] + pbp[t2] * 8];
#pragma unroll
      for (int mt = 0; mt < 3; ++mt)
        facc[t2][mt] = __builtin_amdgcn_mfma_f32_16x16x32_bf16(a[mt], b, facc[t2][mt], 0, 0, 0);
    }
  }

  // epilogue: gated -> LDS (grouped co layout) -> contiguous global write
  __syncthreads();
#pragma unroll
  for (int t2 = 0; t2 < 2; ++t2) {
#pragma unroll
    for (int mt = 0; mt < 3; ++mt) {
      int co0 = mt * 16 + lk * 4;
      if (co0 < NF) {
        bf16x4 ov;
#pragma unroll
        for (int r = 0; r < 4; ++r)
          ov[r] = (bf16)(facc[t2][mt][r] * (float)gv[t2][mt][r]);
        *(bf16x4*)&xs[(co0 >> 3) * 2600 + pixv[t2] * 8 + (co0 & 7)] = ov;
      }
    }
  }
  __syncthreads();

  // 2560 units of 8B -> contiguous 1280B row runs (256 px * 10 bf16x4 units)
  for (int u = tid; u < 2560; u += 512) {
    int pix = u / 10, c4 = u - pix * 10;
    bf16x4 v = *(const bf16x4*)&xs[(c4 >> 1) * 2600 + pix * 8 + (c4 & 1) * 4];
    size_t gb = ((size_t)n * HW * HW + (size_t)(Y0 + (pix >> 4)) * HW + (X0 + (pix & 15))) * NF;
    *(bf16x4*)&gated[gb + c4 * 4] = v;
  }
}

// ---------------- K1 (fallback, NCHW staging; R3 version) ----------------
#define K1_RW 18
__global__ __launch_bounds__(512, 6)
void k1_gate_nchw(const float* __restrict__ x, const float* __restrict__ b2,
                  const bf16* __restrict__ ws, bf16* __restrict__ gated) {
  __shared__ bf16 xs[K1_RW * K1_RW * NF];

  const int tid  = threadIdx.x;
  const int lane = tid & 63;
  const int wid  = tid >> 6;
  const int l15  = lane & 15;
  const int lk   = lane >> 4;
  const int n    = blockIdx.z;
  const int X0   = blockIdx.x * 16;
  const int Y0   = blockIdx.y * 16;

  const bf16* W3A = ws;
  const bf16* W2A = ws + 2 * MPAD * KPAD;

  const float* xn = x + (size_t)n * NF * HW * HW;
  for (int i = tid; i < K1_RW * K1_RW * NF / 2; i += 512) {
    int cih = i / (K1_RW * K1_RW);
    int rem = i - cih * (K1_RW * K1_RW);
    int ci  = cih * 2;
    int yy  = rem / K1_RW, xx = rem - yy * K1_RW;
    int gy  = Y0 - 1 + yy, gx = X0 - 1 + xx;
    float v0 = 0.f, v1 = 0.f;
    if ((unsigned)gy < HW && (unsigned)gx < HW) {
      const float* p = xn + (size_t)ci * HW * HW + gy * HW + gx;
      v0 = p[0];
      v1 = p[HW * HW];
    }
    bf16x2 pr; pr[0] = (bf16)v0; pr[1] = (bf16)v1;
    *(bf16x2*)&xs[rem * NF + ci] = pr;
  }

  int off3[12];
#pragma unroll
  for (int kk = 0; kk < 12; ++kk) {
    int k0 = kk * 32 + lk * 8;
    int kc = (k0 < 360) ? k0 : 0;
    int tap = kc / NF, ci0 = kc - tap * NF;
    int ky = tap / 3, kx = tap - ky * 3;
    off3[kk] = (ky * K1_RW + kx) * NF + ci0;
  }
  int pb[2];
#pragma unroll
  for (int t2 = 0; t2 < 2; ++t2) {
    int pix = (wid * 2 + t2) * 16 + l15;
    int py = pix >> 4, px = pix & 15;
    pb[t2] = (py * K1_RW + px) * NF;
  }
  float b2v[3][4];
#pragma unroll
  for (int mt = 0; mt < 3; ++mt)
#pragma unroll
    for (int r = 0; r < 4; ++r) {
      int co = mt * 16 + lk * 4 + r;
      b2v[mt][r] = (co < NF) ? b2[co] : 0.f;
    }

  __syncthreads();

  bf16x4 gv[2][3];
  {
    f32x4 g[2][3];
#pragma unroll
    for (int t2 = 0; t2 < 2; ++t2)
#pragma unroll
      for (int mt = 0; mt < 3; ++mt) g[t2][mt] = f32x4{0, 0, 0, 0};
#pragma unroll
    for (int kk = 0; kk < 2; ++kk) {
      int k0 = kk * 32 + lk * 8;
      int goff = (K1_RW + 1) * NF + ((k0 < NF) ? k0 : 0);
      bf16x8 a[3];
#pragma unroll
      for (int mt = 0; mt < 3; ++mt)
        a[mt] = *(const bf16x8*)&W2A[(mt * 16 + l15) * 64 + k0];
#pragma unroll
      for (int t2 = 0; t2 < 2; ++t2) {
        bf16x8 b = *(const bf16x8*)&xs[pb[t2] + goff];
#pragma unroll
        for (int mt = 0; mt < 3; ++mt)
          g[t2][mt] = __builtin_amdgcn_mfma_f32_16x16x32_bf16(a[mt], b, g[t2][mt], 0, 0, 0);
      }
    }
#pragma unroll
    for (int t2 = 0; t2 < 2; ++t2)
#pragma unroll
      for (int mt = 0; mt < 3; ++mt)
#pragma unroll
        for (int r = 0; r < 4; ++r)
          gv[t2][mt][r] = (bf16)(1.f / (1.f + __expf(-(g[t2][mt][r] + b2v[mt][r]))));
  }

  f32x4 facc[2][3];
#pragma unroll
  for (int t2 = 0; t2 < 2; ++t2)
#pragma unroll
    for (int mt = 0; mt < 3; ++mt) facc[t2][mt] = f32x4{0, 0, 0, 0};

#pragma unroll
  for (int kk = 0; kk < 12; ++kk) {
    bf16x8 a[3];
#pragma unroll
    for (int mt = 0; mt < 3; ++mt)
      a[mt] = *(const bf16x8*)&W3A[(mt * 16 + l15) * KPAD + kk * 32 + lk * 8];
#pragma unroll
    for (int t2 = 0; t2 < 2; ++t2) {
      bf16x8 b = *(const bf16x8*)&xs[pb[t2] + off3[kk]];
#pragma unroll
      for (int mt = 0; mt < 3; ++mt)
        facc[t2][mt] = __builtin_amdgcn_mfma_f32_16x16x32_bf16(a[mt], b, facc[t2][mt], 0, 0, 0);
    }
  }

#pragma unroll
  for (int t2 = 0; t2 < 2; ++t2) {
    int pix = (wid * 2 + t2) * 16 + l15;
    int py = pix >> 4, px = pix & 15;
    size_t base = ((size_t)n * HW * HW + (size_t)(Y0 + py) * HW + (X0 + px)) * NF;
#pragma unroll
    for (int mt = 0; mt < 3; ++mt) {
      int co0 = mt * 16 + lk * 4;
      if (co0 < NF) {
        bf16x4 ov;
#pragma unroll
        for (int r = 0; r < 4; ++r)
          ov[r] = (bf16)(facc[t2][mt][r] * (float)gv[t2][mt][r]);
        *(bf16x4*)&gated[base + co0] = ov;
      }
    }
  }
}

// ---------------- K2: out = conv3x3(gated, w4), f32 NCHW ----------------
// tile 32x8, region 34x10. LDS grouped: stride 2728 elems (5456 B).
__global__ __launch_bounds__(512, 8)
void k2_conv(const bf16* __restrict__ gated, const bf16* __restrict__ ws,
             float* __restrict__ out) {
  __shared__ bf16 os[5 * 2728];            // 27280 B

  const int tid  = threadIdx.x;
  const int lane = tid & 63;
  const int wid  = tid >> 6;
  const int l15  = lane & 15;
  const int lk   = lane >> 4;
  const int n    = blockIdx.z;
  const int X0   = blockIdx.x * 32;
  const int Y0   = blockIdx.y * 8;

  const bf16* W4A = ws + MPAD * KPAD;

  for (int i = tid; i < 1700; i += 512) {
    int r   = i / 170;
    int rem = i - r * 170;
    int p   = rem / 5, c = rem - p * 5;
    int gy  = Y0 - 1 + r, gx = X0 - 1 + p;
    bf16x8 v = {};
    if ((unsigned)gy < HW && (unsigned)gx < HW)
      v = *(const bf16x8*)&gated[((size_t)n * HW * HW + (size_t)gy * HW + gx) * NF + c * 8];
    *(bf16x8*)&os[c * 2728 + (r * 34 + p) * 8] = v;
  }

  int gp4[12];
#pragma unroll
  for (int kk = 0; kk < 12; ++kk) {
    int k0 = kk * 32 + lk * 8;
    int kc = (k0 < 360) ? k0 : 0;
    int tap = kc / NF, ci0 = kc - tap * NF;
    int ky = tap / 3, kx = tap - ky * 3;
    gp4[kk] = (ci0 >> 3) * 2728 + (ky * 34 + kx) * 8;
  }
  int pbp[2];
#pragma unroll
  for (int t2 = 0; t2 < 2; ++t2) {
    int px = t2 * 16 + l15;                // py = wid
    pbp[t2] = wid * 34 + px;
  }

  __syncthreads();

  f32x4 acc[2][3];
#pragma unroll
  for (int t2 = 0; t2 < 2; ++t2)
#pragma unroll
    for (int mt = 0; mt < 3; ++mt) acc[t2][mt] = f32x4{0, 0, 0, 0};

#pragma unroll
  for (int kk = 0; kk < 12; ++kk) {
    bf16x8 a[3];
#pragma unroll
    for (int mt = 0; mt < 3; ++mt)
      a[mt] = *(const bf16x8*)&W4A[(mt * 16 + l15) * KPAD + kk * 32 + lk * 8];
#pragma unroll
    for (int t2 = 0; t2 < 2; ++t2) {
      bf16x8 b = *(const bf16x8*)&os[gp4[kk] + pbp[t2] * 8];
#pragma unroll
      for (int mt = 0; mt < 3; ++mt)
        acc[t2][mt] = __builtin_amdgcn_mfma_f32_16x16x32_bf16(a[mt], b, acc[t2][mt], 0, 0, 0);
    }
  }

  // store f32 NCHW; t2 inner so 64B halves merge into 128B lines
  float* on = out + (size_t)n * NF * HW * HW + (size_t)(Y0 + wid) * HW + X0;
#pragma unroll
  for (int mt = 0; mt < 3; ++mt)
#pragma unroll
    for (int r = 0; r < 4; ++r) {
      int co = mt * 16 + lk * 4 + r;
      if (co < NF) {
#pragma unroll
        for (int t2 = 0; t2 < 2; ++t2)
          on[(size_t)co * HW * HW + t2 * 16 + l15] = acc[t2][mt][r];
      }
    }
}

extern "C" void kernel_launch(void* const* d_in, const int* in_sizes, int n_in,
                              void* d_out, int out_size, void* d_ws, size_t ws_size,
                              hipStream_t stream) {
  const float* x  = (const float*)d_in[0];
  const float* w2 = (const float*)d_in[1];
  const float* b2 = (const float*)d_in[2];
  const float* w3 = (const float*)d_in[3];
  const float* w4 = (const float*)d_in[4];
  float* out = (float*)d_out;
  bf16* ws   = (bf16*)d_ws;

  hipLaunchKernelGGL(prep_weights, dim3(72), dim3(256), 0, stream, w2, w3, w4, ws);

  bf16* gated = ws + GATED_ELEM_OFF;
  if (ws_size >= WS_FULL) {
    bf16* xT = ws + XT_ELEM_OFF;
    hipLaunchKernelGGL(transpose_nhwc, dim3(256, 16), dim3(256), 0, stream, x, xT);
    hipLaunchKernelGGL(k1_gate_xt, dim3(16, 16, 16), dim3(512), 0, stream,
                       xT, b2, ws, gated);
  } else {
    hipLaunchKernelGGL(k1_gate_nchw, dim3(16, 16, 16), dim3(512), 0, stream,
                       x, b2, ws, gated);
  }
  hipLaunchKernelGGL(k2_conv, dim3(8, 32, 16), dim3(512), 0, stream,
                     gated, ws, out);
}